// Round 1
// baseline (986.222 us; speedup 1.0000x reference)
//
#include <hip/hip_runtime.h>
#include <hip/hip_bf16.h>

typedef __bf16 bf16x8 __attribute__((ext_vector_type(8)));
typedef float  f32x4  __attribute__((ext_vector_type(4)));

#define MFMA16(a, b, c) __builtin_amdgcn_mfma_f32_16x16x32_bf16(a, b, c, 0, 0, 0)

// Problem constants
// B=8 T=192 N=64 D=512 H=8 DH=64 C=8 ; M = B*T = 1536 rows per n

// ---------------------------------------------------------------------------
// Kernel 1: cast Wq_w / Wv_w / proj_w (stored [e][d]) to bf16, same layout.
// B-fragment wants B[k=d][col=e] = W[e][d] -> LDS rows indexed by e, contiguous
// along d. [e][d] storage is already what we need.
__global__ void k_cast3(const float* __restrict__ wq, const float* __restrict__ wv,
                        const float* __restrict__ wp,
                        __bf16* __restrict__ oq, __bf16* __restrict__ ov,
                        __bf16* __restrict__ op) {
    int i = blockIdx.x * 256 + threadIdx.x;  // 262144 total
    oq[i] = (__bf16)wq[i];
    ov[i] = (__bf16)wv[i];
    op[i] = (__bf16)wp[i];
}

// Kernel 2: Wk stored [c][d][e]; K-proj needs B[k=d][col=e] = Wk[c][d][e], so to
// match the [e][d] row-major convention of the GEMM's B loader, store [c][e][d].
__global__ void k_twk(const float* __restrict__ wk, __bf16* __restrict__ o) {
    int i = blockIdx.x * 256 + threadIdx.x;  // 2097152 total, read-coalesced
    int c = i >> 18;
    int r = i & 262143;
    int d = r >> 9;
    int e = r & 511;
    o[(c << 18) + (e << 9) + d] = (__bf16)wk[i];
}

// ---------------------------------------------------------------------------
// Kernel 3: fused Q/K/V projection. Grid (m_tile=24, e_tile=8, n=64), 256 thr.
// Per block: fixed n (so K weight is uniform), 64x64 output tile for each of
// Q, K, V sharing one A tile (x rows for this n, fp32 -> bf16 on staging).
__launch_bounds__(256)
__global__ void k_qkv(const float* __restrict__ x,
                      const __bf16* __restrict__ WqE, const __bf16* __restrict__ WvE,
                      const __bf16* __restrict__ WkE,
                      const float* __restrict__ bq, const float* __restrict__ bv,
                      const float* __restrict__ bk, const int* __restrict__ cid,
                      __bf16* __restrict__ Qw, __bf16* __restrict__ Kw,
                      __bf16* __restrict__ Vw) {
    const int n  = blockIdx.z;
    const int m0 = blockIdx.x * 64;
    const int e0 = blockIdx.y * 64;
    const int c  = cid[n];
    const __bf16* Wkc = WkE + ((size_t)c << 18);

    // stride 40 bf16 = 80 B: 16B-aligned rows, 2-way-max bank aliasing (free)
    __shared__ __align__(16) __bf16 As[64 * 40];
    __shared__ __align__(16) __bf16 Bq[64 * 40];
    __shared__ __align__(16) __bf16 Bk[64 * 40];
    __shared__ __align__(16) __bf16 Bv[64 * 40];

    const int tid  = threadIdx.x;
    const int lane = tid & 63;
    const int w    = tid >> 6;          // wave 0..3
    const int wm   = w >> 1, wn = w & 1;
    const int l15  = lane & 15, qd = lane >> 4;
    const int r    = tid >> 2, p = tid & 3;  // staging: row 0..63, part 0..3

    f32x4 acc[3][2][2];
#pragma unroll
    for (int a = 0; a < 3; ++a)
#pragma unroll
        for (int i = 0; i < 2; ++i)
#pragma unroll
            for (int j = 0; j < 2; ++j) acc[a][i][j] = (f32x4){0.f, 0.f, 0.f, 0.f};

    // x[b][t][n][d]: row m=(b*T+t) at offset (m*64+n)*512
    const float*  xrow  = x + ((size_t)(m0 + r) * 64 + n) * 512;
    const __bf16* wqrow = WqE + ((size_t)(e0 + r) << 9);
    const __bf16* wvrow = WvE + ((size_t)(e0 + r) << 9);
    const __bf16* wkrow = Wkc + ((size_t)(e0 + r) << 9);

    for (int kk = 0; kk < 16; ++kk) {
        const int k0 = kk * 32 + 8 * p;
        float4 f0 = *(const float4*)(xrow + k0);
        float4 f1 = *(const float4*)(xrow + k0 + 4);
        bf16x8 a8;
        a8[0] = (__bf16)f0.x; a8[1] = (__bf16)f0.y; a8[2] = (__bf16)f0.z; a8[3] = (__bf16)f0.w;
        a8[4] = (__bf16)f1.x; a8[5] = (__bf16)f1.y; a8[6] = (__bf16)f1.z; a8[7] = (__bf16)f1.w;
        bf16x8 q8 = *(const bf16x8*)(wqrow + k0);
        bf16x8 k8 = *(const bf16x8*)(wkrow + k0);
        bf16x8 v8 = *(const bf16x8*)(wvrow + k0);
        *(bf16x8*)&As[r * 40 + 8 * p] = a8;
        *(bf16x8*)&Bq[r * 40 + 8 * p] = q8;
        *(bf16x8*)&Bk[r * 40 + 8 * p] = k8;
        *(bf16x8*)&Bv[r * 40 + 8 * p] = v8;
        __syncthreads();

        // A[m][k]: lane holds m=l15, k=qd*8+j ; B (as Bt[e][k]): col=l15, k=qd*8+j
        bf16x8 a0 = *(const bf16x8*)&As[(wm * 32 + l15) * 40 + 8 * qd];
        bf16x8 a1 = *(const bf16x8*)&As[(wm * 32 + 16 + l15) * 40 + 8 * qd];
#pragma unroll
        for (int nb = 0; nb < 2; ++nb) {
            const int bi = (wn * 32 + nb * 16 + l15) * 40 + 8 * qd;
            bf16x8 fq = *(const bf16x8*)&Bq[bi];
            bf16x8 fk = *(const bf16x8*)&Bk[bi];
            bf16x8 fv = *(const bf16x8*)&Bv[bi];
            acc[0][0][nb] = MFMA16(a0, fq, acc[0][0][nb]);
            acc[0][1][nb] = MFMA16(a1, fq, acc[0][1][nb]);
            acc[1][0][nb] = MFMA16(a0, fk, acc[1][0][nb]);
            acc[1][1][nb] = MFMA16(a1, fk, acc[1][1][nb]);
            acc[2][0][nb] = MFMA16(a0, fv, acc[2][0][nb]);
            acc[2][1][nb] = MFMA16(a1, fv, acc[2][1][nb]);
        }
        __syncthreads();
    }

    float biasq[2], biask[2], biasv[2];
#pragma unroll
    for (int nb = 0; nb < 2; ++nb) {
        int e = e0 + wn * 32 + nb * 16 + l15;
        biasq[nb] = bq[e];
        biask[nb] = bk[(c << 9) + e];
        biasv[nb] = bv[e];
    }
    // C/D: row = qd*4 + rx, col = l15. Output layout [B][N][T][D].
#pragma unroll
    for (int mb = 0; mb < 2; ++mb) {
#pragma unroll
        for (int rx = 0; rx < 4; ++rx) {
            int m  = m0 + wm * 32 + mb * 16 + qd * 4 + rx;  // = b*192 + t
            int bb = m / 192;
            int tt = m - bb * 192;
            size_t ro = ((size_t)(bb * 64 + n) * 192 + tt) << 9;
#pragma unroll
            for (int nb = 0; nb < 2; ++nb) {
                int e = e0 + wn * 32 + nb * 16 + l15;
                Qw[ro + e] = (__bf16)(acc[0][mb][nb][rx] + biasq[nb]);
                Kw[ro + e] = (__bf16)(acc[1][mb][nb][rx] + biask[nb]);
                Vw[ro + e] = (__bf16)(acc[2][mb][nb][rx] + biasv[nb]);
            }
        }
    }
}

// ---------------------------------------------------------------------------
// Kernel 4: attention for one (b,n,h) per block. 768 thr = 12 waves, each wave
// owns one 16-row Q strip (12*16 = 192 = T). Q frags in registers; K and V^T
// staged in LDS; S kept in registers (12 col-tiles x f32x4); softmax reduced
// with __shfl_xor inside each 16-lane quarter; P written to a wave-private LDS
// strip to convert C-layout -> A-layout for the PV MFMA.
__launch_bounds__(768)
__global__ void k_attn(const __bf16* __restrict__ Qw, const __bf16* __restrict__ Kw,
                       const __bf16* __restrict__ Vw, __bf16* __restrict__ Ow) {
    const int h = blockIdx.x, n = blockIdx.y, b = blockIdx.z;
    __shared__ __align__(16) __bf16 Ks[192 * 72];   // [s][k]   27648 B
    __shared__ __align__(16) __bf16 Vt[64 * 200];   // [e][s]   25600 B
    __shared__ __align__(16) __bf16 Ps[192 * 200];  // [t][s]   76800 B

    const int tid  = threadIdx.x;
    const int lane = tid & 63, w = tid >> 6;  // wave 0..11
    const int l15  = lane & 15, qd = lane >> 4;
    const size_t base = ((size_t)((b * 64 + n) * 192) << 9) + h * 64;

    for (int i = tid; i < 1536; i += 768) {  // K: 192 rows x 64 bf16
        int row = i >> 3, pp = i & 7;
        *(bf16x8*)&Ks[row * 72 + 8 * pp] =
            *(const bf16x8*)(Kw + base + ((size_t)row << 9) + 8 * pp);
    }
    for (int i = tid; i < 12288; i += 768) {  // V transposed
        int s = i >> 6, e = i & 63;
        Vt[e * 200 + s] = Vw[base + ((size_t)s << 9) + e];
    }
    __syncthreads();

    // Q fragments for this wave's rows [16w, 16w+16): 2 k-chunks of 32
    const __bf16* qp = Qw + base + ((size_t)(16 * w + l15) << 9) + 8 * qd;
    bf16x8 aq0 = *(const bf16x8*)(qp);
    bf16x8 aq1 = *(const bf16x8*)(qp + 32);

    f32x4 S[12];
#pragma unroll
    for (int ct = 0; ct < 12; ++ct) {
        f32x4 acc = (f32x4){0.f, 0.f, 0.f, 0.f};
        bf16x8 b0 = *(const bf16x8*)&Ks[(16 * ct + l15) * 72 + 8 * qd];
        bf16x8 b1 = *(const bf16x8*)&Ks[(16 * ct + l15) * 72 + 32 + 8 * qd];
        acc = MFMA16(aq0, b0, acc);
        acc = MFMA16(aq1, b1, acc);
        S[ct] = acc;
    }

    // lane holds rows 4*qd + rx (rx=0..3), col = l15 + 16*ct
    float mx[4] = {-1e30f, -1e30f, -1e30f, -1e30f};
#pragma unroll
    for (int ct = 0; ct < 12; ++ct)
#pragma unroll
        for (int rx = 0; rx < 4; ++rx) mx[rx] = fmaxf(mx[rx], S[ct][rx]);
#pragma unroll
    for (int mk = 1; mk < 16; mk <<= 1)
#pragma unroll
        for (int rx = 0; rx < 4; ++rx) mx[rx] = fmaxf(mx[rx], __shfl_xor(mx[rx], mk, 64));

    const float sc = 0.125f * 1.44269504088896f;  // 1/sqrt(64) * log2(e)
    float sm[4] = {0.f, 0.f, 0.f, 0.f};
#pragma unroll
    for (int ct = 0; ct < 12; ++ct) {
#pragma unroll
        for (int rx = 0; rx < 4; ++rx) {
            float pe = exp2f((S[ct][rx] - mx[rx]) * sc);
            sm[rx] += pe;
            Ps[(w * 16 + qd * 4 + rx) * 200 + 16 * ct + l15] = (__bf16)pe;
        }
    }
#pragma unroll
    for (int mk = 1; mk < 16; mk <<= 1)
#pragma unroll
        for (int rx = 0; rx < 4; ++rx) sm[rx] += __shfl_xor(sm[rx], mk, 64);

    __syncthreads();  // P strips are wave-local; barrier is cheap insurance

    float inv[4];
#pragma unroll
    for (int rx = 0; rx < 4; ++rx) inv[rx] = 1.f / sm[rx];

#pragma unroll
    for (int et = 0; et < 4; ++et) {
        f32x4 acc = (f32x4){0.f, 0.f, 0.f, 0.f};
#pragma unroll
        for (int sn = 0; sn < 6; ++sn) {
            bf16x8 pa = *(const bf16x8*)&Ps[(w * 16 + l15) * 200 + sn * 32 + 8 * qd];
            bf16x8 vb = *(const bf16x8*)&Vt[(et * 16 + l15) * 200 + sn * 32 + 8 * qd];
            acc = MFMA16(pa, vb, acc);
        }
#pragma unroll
        for (int rx = 0; rx < 4; ++rx) {
            int t = 16 * w + 4 * qd + rx;
            Ow[base + ((size_t)t << 9) + et * 16 + l15] = (__bf16)(acc[rx] * inv[rx]);
        }
    }
}

// ---------------------------------------------------------------------------
// Kernel 5: output projection. Same tile scheme as k_qkv; A = Ow (bf16,
// [B][N][T][D] rows gathered per n), output fp32 [B][T][N][D].
__launch_bounds__(256)
__global__ void k_proj(const __bf16* __restrict__ Ow, const __bf16* __restrict__ WpE,
                       const float* __restrict__ bp, float* __restrict__ out) {
    const int n  = blockIdx.z;
    const int m0 = blockIdx.x * 64;
    const int e0 = blockIdx.y * 64;
    __shared__ __align__(16) __bf16 As[64 * 40];
    __shared__ __align__(16) __bf16 Bs[64 * 40];
    const int tid  = threadIdx.x;
    const int lane = tid & 63, w = tid >> 6;
    const int wm   = w >> 1, wn = w & 1;
    const int l15  = lane & 15, qd = lane >> 4;
    const int r    = tid >> 2, p = tid & 3;

    f32x4 acc[2][2];
#pragma unroll
    for (int i = 0; i < 2; ++i)
#pragma unroll
        for (int j = 0; j < 2; ++j) acc[i][j] = (f32x4){0.f, 0.f, 0.f, 0.f};

    int m  = m0 + r;
    int bb = m / 192;
    int tt = m - bb * 192;
    const __bf16* arow = Ow + (((size_t)(bb * 64 + n) * 192 + tt) << 9);
    const __bf16* brow = WpE + ((size_t)(e0 + r) << 9);

    for (int kk = 0; kk < 16; ++kk) {
        const int k0 = kk * 32 + 8 * p;
        *(bf16x8*)&As[r * 40 + 8 * p] = *(const bf16x8*)(arow + k0);
        *(bf16x8*)&Bs[r * 40 + 8 * p] = *(const bf16x8*)(brow + k0);
        __syncthreads();
        bf16x8 a0 = *(const bf16x8*)&As[(wm * 32 + l15) * 40 + 8 * qd];
        bf16x8 a1 = *(const bf16x8*)&As[(wm * 32 + 16 + l15) * 40 + 8 * qd];
#pragma unroll
        for (int nb = 0; nb < 2; ++nb) {
            bf16x8 fb = *(const bf16x8*)&Bs[(wn * 32 + nb * 16 + l15) * 40 + 8 * qd];
            acc[0][nb] = MFMA16(a0, fb, acc[0][nb]);
            acc[1][nb] = MFMA16(a1, fb, acc[1][nb]);
        }
        __syncthreads();
    }

    float bias[2];
#pragma unroll
    for (int nb = 0; nb < 2; ++nb) bias[nb] = bp[e0 + wn * 32 + nb * 16 + l15];
#pragma unroll
    for (int mb = 0; mb < 2; ++mb) {
#pragma unroll
        for (int rx = 0; rx < 4; ++rx) {
            int mm = m0 + wm * 32 + mb * 16 + qd * 4 + rx;  // = b*T + t
            size_t ro = ((size_t)(mm * 64 + n)) << 9;       // [B,T,N,D] row
#pragma unroll
            for (int nb = 0; nb < 2; ++nb) {
                int e = e0 + wn * 32 + nb * 16 + l15;
                out[ro + e] = acc[mb][nb][rx] + bias[nb];
            }
        }
    }
}

// ---------------------------------------------------------------------------
extern "C" void kernel_launch(void* const* d_in, const int* in_sizes, int n_in,
                              void* d_out, int out_size, void* d_ws, size_t ws_size,
                              hipStream_t stream) {
    const float* x    = (const float*)d_in[0];
    const float* Wq_w = (const float*)d_in[1];
    const float* Wq_b = (const float*)d_in[2];
    const float* Wv_w = (const float*)d_in[3];
    const float* Wv_b = (const float*)d_in[4];
    const float* Wk   = (const float*)d_in[5];
    const float* bk   = (const float*)d_in[6];
    const float* Wp   = (const float*)d_in[7];
    const float* bp   = (const float*)d_in[8];
    const int*   cid  = (const int*)d_in[9];
    float* out = (float*)d_out;

    // Workspace layout (bf16 elements):
    //   WqE 256K | WvE 256K | WpE 256K | WkE 8x256K | Qw,Kw,Vw,Ow 4x50331648
    // total = 408,420,352 bytes
    __bf16* WqE = (__bf16*)d_ws;
    __bf16* WvE = WqE + (1 << 18);
    __bf16* WpE = WvE + (1 << 18);
    __bf16* WkE = WpE + (1 << 18);
    __bf16* Qw  = WkE + (8 << 18);
    __bf16* Kw  = Qw + 50331648LL;
    __bf16* Vw  = Kw + 50331648LL;
    __bf16* Ow  = Vw + 50331648LL;

    k_cast3<<<1024, 256, 0, stream>>>(Wq_w, Wv_w, Wp, WqE, WvE, WpE);
    k_twk<<<8192, 256, 0, stream>>>(Wk, WkE);
    k_qkv<<<dim3(24, 8, 64), 256, 0, stream>>>(x, WqE, WvE, WkE, Wq_b, Wv_b, bk, cid,
                                               Qw, Kw, Vw);
    k_attn<<<dim3(8, 64, 8), 768, 0, stream>>>(Qw, Kw, Vw, Ow);
    k_proj<<<dim3(24, 8, 64), 256, 0, stream>>>(Ow, WpE, bp, out);
}

// Round 2
// 858.564 us; speedup vs baseline: 1.1487x; 1.1487x over previous
//
#include <hip/hip_runtime.h>
#include <hip/hip_bf16.h>

typedef __bf16 bf16x8 __attribute__((ext_vector_type(8)));
typedef float  f32x4  __attribute__((ext_vector_type(4)));

#define MFMA16(a, b, c) __builtin_amdgcn_mfma_f32_16x16x32_bf16(a, b, c, 0, 0, 0)

// async global->LDS, 16 B per lane. LDS dest is wave-uniform base + lane*16.
__device__ __forceinline__ void async16(const __bf16* g, __bf16* l) {
    __builtin_amdgcn_global_load_lds(
        (const __attribute__((address_space(1))) unsigned int*)g,
        (__attribute__((address_space(3))) unsigned int*)l, 16, 0, 0);
}

// B=8 T=192 N=64 D=512 H=8 DH=64 C=8 ; per-n GEMM rows M = B*T = 1536

// ---------------------------------------------------------------------------
// cast Wq_w / Wv_w / proj_w ([e][d] fp32) to bf16, same layout
__global__ void k_cast3(const float* __restrict__ wq, const float* __restrict__ wv,
                        const float* __restrict__ wp,
                        __bf16* __restrict__ oq, __bf16* __restrict__ ov,
                        __bf16* __restrict__ op) {
    int i = blockIdx.x * 256 + threadIdx.x;
    oq[i] = (__bf16)wq[i];
    ov[i] = (__bf16)wv[i];
    op[i] = (__bf16)wp[i];
}

// Wk [c][d][e] fp32 -> bf16 [c][e][d]
__global__ void k_twk(const float* __restrict__ wk, __bf16* __restrict__ o) {
    int i = blockIdx.x * 256 + threadIdx.x;
    int c = i >> 18;
    int r = i & 262143;
    int d = r >> 9;
    int e = r & 511;
    o[(c << 18) + (e << 9) + d] = (__bf16)wk[i];
}

// x fp32 [B,T,N,D] -> bf16 same layout (so GEMM staging is pure async DMA)
__global__ void k_castx(const float* __restrict__ x, __bf16* __restrict__ o) {
    size_t i = ((size_t)blockIdx.x * 256 + threadIdx.x) * 8;
    float4 f0 = *(const float4*)(x + i);
    float4 f1 = *(const float4*)(x + i + 4);
    bf16x8 v;
    v[0] = (__bf16)f0.x; v[1] = (__bf16)f0.y; v[2] = (__bf16)f0.z; v[3] = (__bf16)f0.w;
    v[4] = (__bf16)f1.x; v[5] = (__bf16)f1.y; v[6] = (__bf16)f1.z; v[7] = (__bf16)f1.w;
    *(bf16x8*)(o + i) = v;
}

// ---------------------------------------------------------------------------
// Fused QKV projection. Grid (m_tile=12, e_tile=8, n=64), 256 thr = 4 waves.
// Block tile: 128 m x 64 e for each of Q/K/V (shared A tile). BK=64.
// All staging via global_load_lds width 16 (no ds_write at all).
__launch_bounds__(256)
__global__ void k_qkv(const __bf16* __restrict__ xb,
                      const __bf16* __restrict__ WqE, const __bf16* __restrict__ WvE,
                      const __bf16* __restrict__ WkE,
                      const float* __restrict__ bq, const float* __restrict__ bv,
                      const float* __restrict__ bk, const int* __restrict__ cid,
                      __bf16* __restrict__ Qw, __bf16* __restrict__ Kw,
                      __bf16* __restrict__ Vw) {
    const int n  = blockIdx.z;
    const int m0 = blockIdx.x * 128;
    const int e0 = blockIdx.y * 64;
    const int c  = cid[n];
    const __bf16* Wkc = WkE + ((size_t)c << 18);

    __shared__ __align__(16) __bf16 As[128 * 64];  // 16 KB
    __shared__ __align__(16) __bf16 Bq[64 * 64];   // 8 KB
    __shared__ __align__(16) __bf16 Bk[64 * 64];
    __shared__ __align__(16) __bf16 Bv[64 * 64];

    const int tid  = threadIdx.x;
    const int lane = tid & 63;
    const int w    = tid >> 6;       // 0..3
    const int wm   = w >> 1, wn = w & 1;
    const int l15  = lane & 15, qd = lane >> 4;
    const int lr   = lane >> 3;      // row within 8-row chunk
    const int lc   = lane & 7;       // 16B column within 128B row

    // staging base pointers (elements); per k-iter add k0
    // A: 16 chunks of 8 rows; wave w owns chunks w*4..w*4+3
    const __bf16* ag = xb + ((size_t)(m0 + w * 32 + lr) * 64 + n) * 512 + lc * 8;
    __bf16*       al = As + w * 2048 + lr * 64 + lc * 8;
    // B: 8 chunks each; wave w owns chunks w*2, w*2+1
    const __bf16* qg = WqE + ((size_t)(e0 + w * 16 + lr) << 9) + lc * 8;
    const __bf16* kg = Wkc + ((size_t)(e0 + w * 16 + lr) << 9) + lc * 8;
    const __bf16* vg = WvE + ((size_t)(e0 + w * 16 + lr) << 9) + lc * 8;
    __bf16*       bl = Bq + w * 1024 + lr * 64 + lc * 8;
    __bf16*       kl = Bk + w * 1024 + lr * 64 + lc * 8;
    __bf16*       vl = Bv + w * 1024 + lr * 64 + lc * 8;

    f32x4 acc[3][4][2];
#pragma unroll
    for (int a = 0; a < 3; ++a)
#pragma unroll
        for (int i = 0; i < 4; ++i)
#pragma unroll
            for (int j = 0; j < 2; ++j) acc[a][i][j] = (f32x4){0.f, 0.f, 0.f, 0.f};

    for (int kk = 0; kk < 8; ++kk) {
        const int k0 = kk * 64;
        __syncthreads();  // prev iter's ds_reads done before overwrite
#pragma unroll
        for (int j = 0; j < 4; ++j) async16(ag + (size_t)j * 262144 + k0, al + j * 512);
#pragma unroll
        for (int j = 0; j < 2; ++j) {
            async16(qg + j * 4096 + k0, bl + j * 512);
            async16(kg + j * 4096 + k0, kl + j * 512);
            async16(vg + j * 4096 + k0, vl + j * 512);
        }
        __syncthreads();  // vmcnt(0) drain: tiles visible

#pragma unroll
        for (int kc = 0; kc < 2; ++kc) {
            const int ko = kc * 32 + 8 * qd;
            bf16x8 a0 = *(const bf16x8*)&As[(wm * 64 + l15) * 64 + ko];
            bf16x8 a1 = *(const bf16x8*)&As[(wm * 64 + 16 + l15) * 64 + ko];
            bf16x8 a2 = *(const bf16x8*)&As[(wm * 64 + 32 + l15) * 64 + ko];
            bf16x8 a3 = *(const bf16x8*)&As[(wm * 64 + 48 + l15) * 64 + ko];
#pragma unroll
            for (int j = 0; j < 2; ++j) {
                const int bi = (wn * 32 + j * 16 + l15) * 64 + ko;
                bf16x8 fq = *(const bf16x8*)&Bq[bi];
                bf16x8 fk = *(const bf16x8*)&Bk[bi];
                bf16x8 fv = *(const bf16x8*)&Bv[bi];
                acc[0][0][j] = MFMA16(a0, fq, acc[0][0][j]);
                acc[0][1][j] = MFMA16(a1, fq, acc[0][1][j]);
                acc[0][2][j] = MFMA16(a2, fq, acc[0][2][j]);
                acc[0][3][j] = MFMA16(a3, fq, acc[0][3][j]);
                acc[1][0][j] = MFMA16(a0, fk, acc[1][0][j]);
                acc[1][1][j] = MFMA16(a1, fk, acc[1][1][j]);
                acc[1][2][j] = MFMA16(a2, fk, acc[1][2][j]);
                acc[1][3][j] = MFMA16(a3, fk, acc[1][3][j]);
                acc[2][0][j] = MFMA16(a0, fv, acc[2][0][j]);
                acc[2][1][j] = MFMA16(a1, fv, acc[2][1][j]);
                acc[2][2][j] = MFMA16(a2, fv, acc[2][2][j]);
                acc[2][3][j] = MFMA16(a3, fv, acc[2][3][j]);
            }
        }
    }

    float biasq[2], biask[2], biasv[2];
#pragma unroll
    for (int j = 0; j < 2; ++j) {
        int e = e0 + wn * 32 + j * 16 + l15;
        biasq[j] = bq[e];
        biask[j] = bk[(c << 9) + e];
        biasv[j] = bv[e];
    }
    // C/D: row = qd*4 + rx, col = l15. Outputs in [B][N][T][D].
#pragma unroll
    for (int i = 0; i < 4; ++i) {
#pragma unroll
        for (int rx = 0; rx < 4; ++rx) {
            int m  = m0 + wm * 64 + i * 16 + qd * 4 + rx;  // = b*192 + t
            int bb = m / 192;
            int tt = m - bb * 192;
            size_t ro = ((size_t)(bb * 64 + n) * 192 + tt) << 9;
#pragma unroll
            for (int j = 0; j < 2; ++j) {
                int e = e0 + wn * 32 + j * 16 + l15;
                Qw[ro + e] = (__bf16)(acc[0][i][j][rx] + biasq[j]);
                Kw[ro + e] = (__bf16)(acc[1][i][j][rx] + biask[j]);
                Vw[ro + e] = (__bf16)(acc[2][i][j][rx] + biasv[j]);
            }
        }
    }
}

// ---------------------------------------------------------------------------
// Attention, one (b,n,h) per block; 12 waves each own one 16-row Q strip.
__launch_bounds__(768)
__global__ void k_attn(const __bf16* __restrict__ Qw, const __bf16* __restrict__ Kw,
                       const __bf16* __restrict__ Vw, __bf16* __restrict__ Ow) {
    const int h = blockIdx.x, n = blockIdx.y, b = blockIdx.z;
    __shared__ __align__(16) __bf16 Ks[192 * 72];
    __shared__ __align__(16) __bf16 Vt[64 * 200];
    __shared__ __align__(16) __bf16 Ps[192 * 200];

    const int tid  = threadIdx.x;
    const int lane = tid & 63, w = tid >> 6;
    const int l15  = lane & 15, qd = lane >> 4;
    const size_t base = ((size_t)((b * 64 + n) * 192) << 9) + h * 64;

    for (int i = tid; i < 1536; i += 768) {
        int row = i >> 3, pp = i & 7;
        *(bf16x8*)&Ks[row * 72 + 8 * pp] =
            *(const bf16x8*)(Kw + base + ((size_t)row << 9) + 8 * pp);
    }
    for (int i = tid; i < 12288; i += 768) {
        int s = i >> 6, e = i & 63;
        Vt[e * 200 + s] = Vw[base + ((size_t)s << 9) + e];
    }
    __syncthreads();

    const __bf16* qp = Qw + base + ((size_t)(16 * w + l15) << 9) + 8 * qd;
    bf16x8 aq0 = *(const bf16x8*)(qp);
    bf16x8 aq1 = *(const bf16x8*)(qp + 32);

    f32x4 S[12];
#pragma unroll
    for (int ct = 0; ct < 12; ++ct) {
        f32x4 acc = (f32x4){0.f, 0.f, 0.f, 0.f};
        bf16x8 b0 = *(const bf16x8*)&Ks[(16 * ct + l15) * 72 + 8 * qd];
        bf16x8 b1 = *(const bf16x8*)&Ks[(16 * ct + l15) * 72 + 32 + 8 * qd];
        acc = MFMA16(aq0, b0, acc);
        acc = MFMA16(aq1, b1, acc);
        S[ct] = acc;
    }

    float mx[4] = {-1e30f, -1e30f, -1e30f, -1e30f};
#pragma unroll
    for (int ct = 0; ct < 12; ++ct)
#pragma unroll
        for (int rx = 0; rx < 4; ++rx) mx[rx] = fmaxf(mx[rx], S[ct][rx]);
#pragma unroll
    for (int mk = 1; mk < 16; mk <<= 1)
#pragma unroll
        for (int rx = 0; rx < 4; ++rx) mx[rx] = fmaxf(mx[rx], __shfl_xor(mx[rx], mk, 64));

    const float sc = 0.125f * 1.44269504088896f;
    float sm[4] = {0.f, 0.f, 0.f, 0.f};
#pragma unroll
    for (int ct = 0; ct < 12; ++ct) {
#pragma unroll
        for (int rx = 0; rx < 4; ++rx) {
            float pe = exp2f((S[ct][rx] - mx[rx]) * sc);
            sm[rx] += pe;
            Ps[(w * 16 + qd * 4 + rx) * 200 + 16 * ct + l15] = (__bf16)pe;
        }
    }
#pragma unroll
    for (int mk = 1; mk < 16; mk <<= 1)
#pragma unroll
        for (int rx = 0; rx < 4; ++rx) sm[rx] += __shfl_xor(sm[rx], mk, 64);

    __syncthreads();

    float inv[4];
#pragma unroll
    for (int rx = 0; rx < 4; ++rx) inv[rx] = 1.f / sm[rx];

#pragma unroll
    for (int et = 0; et < 4; ++et) {
        f32x4 acc = (f32x4){0.f, 0.f, 0.f, 0.f};
#pragma unroll
        for (int sn = 0; sn < 6; ++sn) {
            bf16x8 pa = *(const bf16x8*)&Ps[(w * 16 + l15) * 200 + sn * 32 + 8 * qd];
            bf16x8 vb = *(const bf16x8*)&Vt[(et * 16 + l15) * 200 + sn * 32 + 8 * qd];
            acc = MFMA16(pa, vb, acc);
        }
#pragma unroll
        for (int rx = 0; rx < 4; ++rx) {
            int t = 16 * w + 4 * qd + rx;
            Ow[base + ((size_t)t << 9) + et * 16 + l15] = (__bf16)(acc[rx] * inv[rx]);
        }
    }
}

// ---------------------------------------------------------------------------
// Output projection: m97-style 128x128 tile, BK=64, async staging.
// Grid (12, 4, 64), 256 thr = 4 waves, each wave 64x64 out.
__launch_bounds__(256)
__global__ void k_proj(const __bf16* __restrict__ Ow, const __bf16* __restrict__ WpE,
                       const float* __restrict__ bp, float* __restrict__ out) {
    const int n  = blockIdx.z;
    const int m0 = blockIdx.x * 128;
    const int e0 = blockIdx.y * 128;
    __shared__ __align__(16) __bf16 As[128 * 64];  // 16 KB
    __shared__ __align__(16) __bf16 Bs[128 * 64];  // 16 KB

    const int tid  = threadIdx.x;
    const int lane = tid & 63, w = tid >> 6;
    const int wm   = w >> 1, wn = w & 1;
    const int l15  = lane & 15, qd = lane >> 4;
    const int lr   = lane >> 3, lc = lane & 7;

    // A rows come from Ow [B,N,T,D]; row m -> (b=m/192, t=m%192)
    const __bf16* agj[4];
#pragma unroll
    for (int j = 0; j < 4; ++j) {
        int m  = m0 + w * 32 + j * 8 + lr;
        int bb = m / 192;
        int tt = m - bb * 192;
        agj[j] = Ow + (((size_t)(bb * 64 + n) * 192 + tt) << 9) + lc * 8;
    }
    __bf16* al = As + w * 2048 + lr * 64 + lc * 8;
    const __bf16* bg = WpE + ((size_t)(e0 + w * 32 + lr) << 9) + lc * 8;
    __bf16*       blp = Bs + w * 2048 + lr * 64 + lc * 8;

    f32x4 acc[4][4];
#pragma unroll
    for (int i = 0; i < 4; ++i)
#pragma unroll
        for (int j = 0; j < 4; ++j) acc[i][j] = (f32x4){0.f, 0.f, 0.f, 0.f};

    for (int kk = 0; kk < 8; ++kk) {
        const int k0 = kk * 64;
        __syncthreads();
#pragma unroll
        for (int j = 0; j < 4; ++j) {
            async16(agj[j] + k0, al + j * 512);
            async16(bg + j * 4096 + k0, blp + j * 512);
        }
        __syncthreads();

#pragma unroll
        for (int kc = 0; kc < 2; ++kc) {
            const int ko = kc * 32 + 8 * qd;
            bf16x8 a0 = *(const bf16x8*)&As[(wm * 64 + l15) * 64 + ko];
            bf16x8 a1 = *(const bf16x8*)&As[(wm * 64 + 16 + l15) * 64 + ko];
            bf16x8 a2 = *(const bf16x8*)&As[(wm * 64 + 32 + l15) * 64 + ko];
            bf16x8 a3 = *(const bf16x8*)&As[(wm * 64 + 48 + l15) * 64 + ko];
#pragma unroll
            for (int j = 0; j < 4; ++j) {
                bf16x8 fb = *(const bf16x8*)&Bs[(wn * 64 + j * 16 + l15) * 64 + ko];
                acc[0][j] = MFMA16(a0, fb, acc[0][j]);
                acc[1][j] = MFMA16(a1, fb, acc[1][j]);
                acc[2][j] = MFMA16(a2, fb, acc[2][j]);
                acc[3][j] = MFMA16(a3, fb, acc[3][j]);
            }
        }
    }

    float bias[4];
#pragma unroll
    for (int j = 0; j < 4; ++j) bias[j] = bp[e0 + wn * 64 + j * 16 + l15];
#pragma unroll
    for (int i = 0; i < 4; ++i) {
#pragma unroll
        for (int rx = 0; rx < 4; ++rx) {
            int m = m0 + wm * 64 + i * 16 + qd * 4 + rx;  // = b*T + t
            size_t ro = ((size_t)(m * 64 + n)) << 9;      // out [B,T,N,D]
#pragma unroll
            for (int j = 0; j < 4; ++j) {
                int e = e0 + wn * 64 + j * 16 + l15;
                out[ro + e] = acc[i][j][rx] + bias[j];
            }
        }
    }
}

// ---------------------------------------------------------------------------
extern "C" void kernel_launch(void* const* d_in, const int* in_sizes, int n_in,
                              void* d_out, int out_size, void* d_ws, size_t ws_size,
                              hipStream_t stream) {
    const float* x    = (const float*)d_in[0];
    const float* Wq_w = (const float*)d_in[1];
    const float* Wq_b = (const float*)d_in[2];
    const float* Wv_w = (const float*)d_in[3];
    const float* Wv_b = (const float*)d_in[4];
    const float* Wk   = (const float*)d_in[5];
    const float* bk   = (const float*)d_in[6];
    const float* Wp   = (const float*)d_in[7];
    const float* bp   = (const float*)d_in[8];
    const int*   cid  = (const int*)d_in[9];
    float* out = (float*)d_out;

    // ws (bf16 elems): WqE|WvE|WpE 3x256K, WkE 8x256K, Qw/Kw/Vw 3x50331648,
    // XO 50331648 (xbf during projections, Ow after attention — disjoint lives)
    __bf16* WqE = (__bf16*)d_ws;
    __bf16* WvE = WqE + (1 << 18);
    __bf16* WpE = WvE + (1 << 18);
    __bf16* WkE = WpE + (1 << 18);
    __bf16* Qw  = WkE + (8 << 18);
    __bf16* Kw  = Qw + 50331648LL;
    __bf16* Vw  = Kw + 50331648LL;
    __bf16* XO  = Vw + 50331648LL;  // xbf, later Ow

    k_cast3<<<1024, 256, 0, stream>>>(Wq_w, Wv_w, Wp, WqE, WvE, WpE);
    k_twk<<<8192, 256, 0, stream>>>(Wk, WkE);
    k_castx<<<24576, 256, 0, stream>>>(x, XO);
    k_qkv<<<dim3(12, 8, 64), 256, 0, stream>>>(XO, WqE, WvE, WkE, Wq_b, Wv_b, bk, cid,
                                               Qw, Kw, Vw);
    k_attn<<<dim3(8, 64, 8), 768, 0, stream>>>(Qw, Kw, Vw, XO);
    k_proj<<<dim3(12, 4, 64), 256, 0, stream>>>(XO, WpE, bp, out);
}

// Round 3
// 812.407 us; speedup vs baseline: 1.2139x; 1.0568x over previous
//
#include <hip/hip_runtime.h>
#include <hip/hip_bf16.h>

typedef __bf16 bf16x8 __attribute__((ext_vector_type(8)));
typedef float  f32x4  __attribute__((ext_vector_type(4)));

#define MFMA16(a, b, c) __builtin_amdgcn_mfma_f32_16x16x32_bf16(a, b, c, 0, 0, 0)

// async global->LDS, 16 B per lane. LDS dest is wave-uniform base + lane*16;
// the GLOBAL address is per-lane free — we exploit that for the XOR swizzle.
__device__ __forceinline__ void async16(const __bf16* g, __bf16* l) {
    __builtin_amdgcn_global_load_lds(
        (const __attribute__((address_space(1))) unsigned int*)g,
        (__attribute__((address_space(3))) unsigned int*)l, 16, 0, 0);
}

// B=8 T=192 N=64 D=512 H=8 DH=64 C=8 ; per-n GEMM rows M = B*T = 1536
// LDS tiles use XOR chunk swizzle: LDS[row][chunk c] = global chunk c ^ (row&7)
// so b128 fragment reads spread over all 32 banks (2 lanes/group = free).

// ---------------------------------------------------------------------------
__global__ void k_cast3(const float* __restrict__ wq, const float* __restrict__ wv,
                        const float* __restrict__ wp,
                        __bf16* __restrict__ oq, __bf16* __restrict__ ov,
                        __bf16* __restrict__ op) {
    int i = blockIdx.x * 256 + threadIdx.x;
    oq[i] = (__bf16)wq[i];
    ov[i] = (__bf16)wv[i];
    op[i] = (__bf16)wp[i];
}

// Wk [c][d][e] fp32 -> bf16 [c][e][d]
__global__ void k_twk(const float* __restrict__ wk, __bf16* __restrict__ o) {
    int i = blockIdx.x * 256 + threadIdx.x;
    int c = i >> 18;
    int r = i & 262143;
    int d = r >> 9;
    int e = r & 511;
    o[(c << 18) + (e << 9) + d] = (__bf16)wk[i];
}

// x fp32 [B,T,N,D] -> bf16 same layout
__global__ void k_castx(const float* __restrict__ x, __bf16* __restrict__ o) {
    size_t i = ((size_t)blockIdx.x * 256 + threadIdx.x) * 8;
    float4 f0 = *(const float4*)(x + i);
    float4 f1 = *(const float4*)(x + i + 4);
    bf16x8 v;
    v[0] = (__bf16)f0.x; v[1] = (__bf16)f0.y; v[2] = (__bf16)f0.z; v[3] = (__bf16)f0.w;
    v[4] = (__bf16)f1.x; v[5] = (__bf16)f1.y; v[6] = (__bf16)f1.z; v[7] = (__bf16)f1.w;
    *(bf16x8*)(o + i) = v;
}

// ---------------------------------------------------------------------------
// Fused QKV projection. Grid (12, 8, 64), 256 thr = 4 waves. 128m x 64e x3.
__launch_bounds__(256)
__global__ void k_qkv(const __bf16* __restrict__ xb,
                      const __bf16* __restrict__ WqE, const __bf16* __restrict__ WvE,
                      const __bf16* __restrict__ WkE,
                      const float* __restrict__ bq, const float* __restrict__ bv,
                      const float* __restrict__ bk, const int* __restrict__ cid,
                      __bf16* __restrict__ Qw, __bf16* __restrict__ Kw,
                      __bf16* __restrict__ Vw) {
    const int n  = blockIdx.z;
    const int m0 = blockIdx.x * 128;
    const int e0 = blockIdx.y * 64;
    const int c  = cid[n];
    const __bf16* Wkc = WkE + ((size_t)c << 18);

    __shared__ __align__(16) __bf16 As[128 * 64];
    __shared__ __align__(16) __bf16 Bq[64 * 64];
    __shared__ __align__(16) __bf16 Bk[64 * 64];
    __shared__ __align__(16) __bf16 Bv[64 * 64];

    const int tid  = threadIdx.x;
    const int lane = tid & 63;
    const int w    = tid >> 6;
    const int wm   = w >> 1, wn = w & 1;
    const int l15  = lane & 15, qd = lane >> 4;
    const int lr   = lane >> 3;        // staging row in 8-row chunk
    const int lc   = lane & 7;         // staging 16B-chunk index
    const int sc8  = (lc ^ lr) * 8;    // swizzled global chunk (elements)
    const int sw   = l15 & 7;          // read-side swizzle key

    const __bf16* ag = xb + ((size_t)(m0 + w * 32 + lr) * 64 + n) * 512 + sc8;
    __bf16*       al = As + w * 2048 + lr * 64 + lc * 8;
    const __bf16* qg = WqE + ((size_t)(e0 + w * 16 + lr) << 9) + sc8;
    const __bf16* kg = Wkc + ((size_t)(e0 + w * 16 + lr) << 9) + sc8;
    const __bf16* vg = WvE + ((size_t)(e0 + w * 16 + lr) << 9) + sc8;
    __bf16*       bl = Bq + w * 1024 + lr * 64 + lc * 8;
    __bf16*       kl = Bk + w * 1024 + lr * 64 + lc * 8;
    __bf16*       vl = Bv + w * 1024 + lr * 64 + lc * 8;

    f32x4 acc[3][4][2];
#pragma unroll
    for (int a = 0; a < 3; ++a)
#pragma unroll
        for (int i = 0; i < 4; ++i)
#pragma unroll
            for (int j = 0; j < 2; ++j) acc[a][i][j] = (f32x4){0.f, 0.f, 0.f, 0.f};

    for (int kk = 0; kk < 8; ++kk) {
        const int k0 = kk * 64;
        __syncthreads();
#pragma unroll
        for (int j = 0; j < 4; ++j) async16(ag + (size_t)j * 262144 + k0, al + j * 512);
#pragma unroll
        for (int j = 0; j < 2; ++j) {
            async16(qg + j * 4096 + k0, bl + j * 512);
            async16(kg + j * 4096 + k0, kl + j * 512);
            async16(vg + j * 4096 + k0, vl + j * 512);
        }
        __syncthreads();

#pragma unroll
        for (int kc = 0; kc < 2; ++kc) {
            const int co = ((kc * 4 + qd) ^ sw) * 8;   // swizzled chunk offset
            bf16x8 a0 = *(const bf16x8*)&As[(wm * 64 + l15) * 64 + co];
            bf16x8 a1 = *(const bf16x8*)&As[(wm * 64 + 16 + l15) * 64 + co];
            bf16x8 a2 = *(const bf16x8*)&As[(wm * 64 + 32 + l15) * 64 + co];
            bf16x8 a3 = *(const bf16x8*)&As[(wm * 64 + 48 + l15) * 64 + co];
#pragma unroll
            for (int j = 0; j < 2; ++j) {
                const int bi = (wn * 32 + j * 16 + l15) * 64 + co;
                bf16x8 fq = *(const bf16x8*)&Bq[bi];
                bf16x8 fk = *(const bf16x8*)&Bk[bi];
                bf16x8 fv = *(const bf16x8*)&Bv[bi];
                acc[0][0][j] = MFMA16(a0, fq, acc[0][0][j]);
                acc[0][1][j] = MFMA16(a1, fq, acc[0][1][j]);
                acc[0][2][j] = MFMA16(a2, fq, acc[0][2][j]);
                acc[0][3][j] = MFMA16(a3, fq, acc[0][3][j]);
                acc[1][0][j] = MFMA16(a0, fk, acc[1][0][j]);
                acc[1][1][j] = MFMA16(a1, fk, acc[1][1][j]);
                acc[1][2][j] = MFMA16(a2, fk, acc[1][2][j]);
                acc[1][3][j] = MFMA16(a3, fk, acc[1][3][j]);
                acc[2][0][j] = MFMA16(a0, fv, acc[2][0][j]);
                acc[2][1][j] = MFMA16(a1, fv, acc[2][1][j]);
                acc[2][2][j] = MFMA16(a2, fv, acc[2][2][j]);
                acc[2][3][j] = MFMA16(a3, fv, acc[2][3][j]);
            }
        }
    }

    float biasq[2], biask[2], biasv[2];
#pragma unroll
    for (int j = 0; j < 2; ++j) {
        int e = e0 + wn * 32 + j * 16 + l15;
        biasq[j] = bq[e];
        biask[j] = bk[(c << 9) + e];
        biasv[j] = bv[e];
    }
#pragma unroll
    for (int i = 0; i < 4; ++i) {
#pragma unroll
        for (int rx = 0; rx < 4; ++rx) {
            int m  = m0 + wm * 64 + i * 16 + qd * 4 + rx;
            int bb = m / 192;
            int tt = m - bb * 192;
            size_t ro = ((size_t)(bb * 64 + n) * 192 + tt) << 9;
#pragma unroll
            for (int j = 0; j < 2; ++j) {
                int e = e0 + wn * 32 + j * 16 + l15;
                Qw[ro + e] = (__bf16)(acc[0][i][j][rx] + biasq[j]);
                Kw[ro + e] = (__bf16)(acc[1][i][j][rx] + biask[j]);
                Vw[ro + e] = (__bf16)(acc[2][i][j][rx] + biasv[j]);
            }
        }
    }
}

// ---------------------------------------------------------------------------
// Attention, one (b,n,h) per block; 12 waves each own one 16-row Q strip.
__launch_bounds__(768)
__global__ void k_attn(const __bf16* __restrict__ Qw, const __bf16* __restrict__ Kw,
                       const __bf16* __restrict__ Vw, __bf16* __restrict__ Ow) {
    const int h = blockIdx.x, n = blockIdx.y, b = blockIdx.z;
    __shared__ __align__(16) __bf16 Ks[192 * 72];   // [s][k] 27.6 KB
    __shared__ __align__(16) __bf16 Vt[64 * 192];   // [e][s] chunk-swizzled 24.6 KB
    __shared__ __align__(16) __bf16 Ps[192 * 200];  // [t][s] 76.8 KB

    const int tid  = threadIdx.x;
    const int lane = tid & 63, w = tid >> 6;
    const int l15  = lane & 15, qd = lane >> 4;
    const size_t base = ((size_t)((b * 64 + n) * 192) << 9) + h * 64;

    for (int i = tid; i < 1536; i += 768) {  // K rows, b128
        int row = i >> 3, pp = i & 7;
        *(bf16x8*)&Ks[row * 72 + 8 * pp] =
            *(const bf16x8*)(Kw + base + ((size_t)row << 9) + 8 * pp);
    }
    // V^T: column gather (coalesced 128B reads) + one swizzled b128 write.
    // Vt[e][s-chunk c] stored at chunk position c ^ (e&7), row stride 192 elems.
#pragma unroll
    for (int rr = 0; rr < 2; ++rr) {
        int idx = rr * 768 + tid;          // 0..1535
        int e = idx & 63, sb = idx >> 6;   // sb 0..23
        bf16x8 v;
#pragma unroll
        for (int j = 0; j < 8; ++j)
            v[j] = Vw[base + (size_t)(sb * 8 + j) * 512 + e];
        *(bf16x8*)&Vt[e * 192 + ((sb ^ (e & 7)) * 8)] = v;
    }
    __syncthreads();

    const __bf16* qp = Qw + base + ((size_t)(16 * w + l15) << 9) + 8 * qd;
    bf16x8 aq0 = *(const bf16x8*)(qp);
    bf16x8 aq1 = *(const bf16x8*)(qp + 32);

    f32x4 S[12];
#pragma unroll
    for (int ct = 0; ct < 12; ++ct) {
        f32x4 acc = (f32x4){0.f, 0.f, 0.f, 0.f};
        bf16x8 b0 = *(const bf16x8*)&Ks[(16 * ct + l15) * 72 + 8 * qd];
        bf16x8 b1 = *(const bf16x8*)&Ks[(16 * ct + l15) * 72 + 32 + 8 * qd];
        acc = MFMA16(aq0, b0, acc);
        acc = MFMA16(aq1, b1, acc);
        S[ct] = acc;
    }

    float mx[4] = {-1e30f, -1e30f, -1e30f, -1e30f};
#pragma unroll
    for (int ct = 0; ct < 12; ++ct)
#pragma unroll
        for (int rx = 0; rx < 4; ++rx) mx[rx] = fmaxf(mx[rx], S[ct][rx]);
#pragma unroll
    for (int mk = 1; mk < 16; mk <<= 1)
#pragma unroll
        for (int rx = 0; rx < 4; ++rx) mx[rx] = fmaxf(mx[rx], __shfl_xor(mx[rx], mk, 64));

    const float sc = 0.125f * 1.44269504088896f;
    float sm[4] = {0.f, 0.f, 0.f, 0.f};
#pragma unroll
    for (int ct = 0; ct < 12; ++ct) {
#pragma unroll
        for (int rx = 0; rx < 4; ++rx) {
            float pe = exp2f((S[ct][rx] - mx[rx]) * sc);
            sm[rx] += pe;
            Ps[(w * 16 + qd * 4 + rx) * 200 + 16 * ct + l15] = (__bf16)pe;
        }
    }
#pragma unroll
    for (int mk = 1; mk < 16; mk <<= 1)
#pragma unroll
        for (int rx = 0; rx < 4; ++rx) sm[rx] += __shfl_xor(sm[rx], mk, 64);

    __syncthreads();

    float inv[4];
#pragma unroll
    for (int rx = 0; rx < 4; ++rx) inv[rx] = 1.f / sm[rx];

#pragma unroll
    for (int et = 0; et < 4; ++et) {
        f32x4 acc = (f32x4){0.f, 0.f, 0.f, 0.f};
#pragma unroll
        for (int sn = 0; sn < 6; ++sn) {
            bf16x8 pa = *(const bf16x8*)&Ps[(w * 16 + l15) * 200 + sn * 32 + 8 * qd];
            bf16x8 vb = *(const bf16x8*)
                &Vt[(et * 16 + l15) * 192 + (((sn * 4 + qd) ^ (l15 & 7)) * 8)];
            acc = MFMA16(pa, vb, acc);
        }
#pragma unroll
        for (int rx = 0; rx < 4; ++rx) {
            int t = 16 * w + 4 * qd + rx;
            Ow[base + ((size_t)t << 9) + et * 16 + l15] = (__bf16)(acc[rx] * inv[rx]);
        }
    }
}

// ---------------------------------------------------------------------------
// Output projection: 128x128 tile, BK=64, async staging, XOR swizzle.
__launch_bounds__(256)
__global__ void k_proj(const __bf16* __restrict__ Ow, const __bf16* __restrict__ WpE,
                       const float* __restrict__ bp, float* __restrict__ out) {
    const int n  = blockIdx.z;
    const int m0 = blockIdx.x * 128;
    const int e0 = blockIdx.y * 128;
    __shared__ __align__(16) __bf16 As[128 * 64];
    __shared__ __align__(16) __bf16 Bs[128 * 64];

    const int tid  = threadIdx.x;
    const int lane = tid & 63, w = tid >> 6;
    const int wm   = w >> 1, wn = w & 1;
    const int l15  = lane & 15, qd = lane >> 4;
    const int lr   = lane >> 3, lc = lane & 7;
    const int sc8  = (lc ^ lr) * 8;
    const int sw   = l15 & 7;

    const __bf16* agj[4];
#pragma unroll
    for (int j = 0; j < 4; ++j) {
        int m  = m0 + w * 32 + j * 8 + lr;
        int bb = m / 192;
        int tt = m - bb * 192;
        agj[j] = Ow + (((size_t)(bb * 64 + n) * 192 + tt) << 9) + sc8;
    }
    __bf16* al = As + w * 2048 + lr * 64 + lc * 8;
    const __bf16* bg  = WpE + ((size_t)(e0 + w * 32 + lr) << 9) + sc8;
    __bf16*       blp = Bs + w * 2048 + lr * 64 + lc * 8;

    f32x4 acc[4][4];
#pragma unroll
    for (int i = 0; i < 4; ++i)
#pragma unroll
        for (int j = 0; j < 4; ++j) acc[i][j] = (f32x4){0.f, 0.f, 0.f, 0.f};

    for (int kk = 0; kk < 8; ++kk) {
        const int k0 = kk * 64;
        __syncthreads();
#pragma unroll
        for (int j = 0; j < 4; ++j) {
            async16(agj[j] + k0, al + j * 512);
            async16(bg + j * 4096 + k0, blp + j * 512);
        }
        __syncthreads();

#pragma unroll
        for (int kc = 0; kc < 2; ++kc) {
            const int co = ((kc * 4 + qd) ^ sw) * 8;
            bf16x8 a0 = *(const bf16x8*)&As[(wm * 64 + l15) * 64 + co];
            bf16x8 a1 = *(const bf16x8*)&As[(wm * 64 + 16 + l15) * 64 + co];
            bf16x8 a2 = *(const bf16x8*)&As[(wm * 64 + 32 + l15) * 64 + co];
            bf16x8 a3 = *(const bf16x8*)&As[(wm * 64 + 48 + l15) * 64 + co];
#pragma unroll
            for (int j = 0; j < 4; ++j) {
                bf16x8 fb = *(const bf16x8*)&Bs[(wn * 64 + j * 16 + l15) * 64 + co];
                acc[0][j] = MFMA16(a0, fb, acc[0][j]);
                acc[1][j] = MFMA16(a1, fb, acc[1][j]);
                acc[2][j] = MFMA16(a2, fb, acc[2][j]);
                acc[3][j] = MFMA16(a3, fb, acc[3][j]);
            }
        }
    }

    float bias[4];
#pragma unroll
    for (int j = 0; j < 4; ++j) bias[j] = bp[e0 + wn * 64 + j * 16 + l15];
#pragma unroll
    for (int i = 0; i < 4; ++i) {
#pragma unroll
        for (int rx = 0; rx < 4; ++rx) {
            int m = m0 + wm * 64 + i * 16 + qd * 4 + rx;
            size_t ro = ((size_t)(m * 64 + n)) << 9;
#pragma unroll
            for (int j = 0; j < 4; ++j) {
                int e = e0 + wn * 64 + j * 16 + l15;
                out[ro + e] = acc[i][j][rx] + bias[j];
            }
        }
    }
}

// ---------------------------------------------------------------------------
extern "C" void kernel_launch(void* const* d_in, const int* in_sizes, int n_in,
                              void* d_out, int out_size, void* d_ws, size_t ws_size,
                              hipStream_t stream) {
    const float* x    = (const float*)d_in[0];
    const float* Wq_w = (const float*)d_in[1];
    const float* Wq_b = (const float*)d_in[2];
    const float* Wv_w = (const float*)d_in[3];
    const float* Wv_b = (const float*)d_in[4];
    const float* Wk   = (const float*)d_in[5];
    const float* bk   = (const float*)d_in[6];
    const float* Wp   = (const float*)d_in[7];
    const float* bp   = (const float*)d_in[8];
    const int*   cid  = (const int*)d_in[9];
    float* out = (float*)d_out;

    __bf16* WqE = (__bf16*)d_ws;
    __bf16* WvE = WqE + (1 << 18);
    __bf16* WpE = WvE + (1 << 18);
    __bf16* WkE = WpE + (1 << 18);
    __bf16* Qw  = WkE + (8 << 18);
    __bf16* Kw  = Qw + 50331648LL;
    __bf16* Vw  = Kw + 50331648LL;
    __bf16* XO  = Vw + 50331648LL;  // xbf during projections, Ow after attn

    k_cast3<<<1024, 256, 0, stream>>>(Wq_w, Wv_w, Wp, WqE, WvE, WpE);
    k_twk<<<8192, 256, 0, stream>>>(Wk, WkE);
    k_castx<<<24576, 256, 0, stream>>>(x, XO);
    k_qkv<<<dim3(12, 8, 64), 256, 0, stream>>>(XO, WqE, WvE, WkE, Wq_b, Wv_b, bk, cid,
                                               Qw, Kw, Vw);
    k_attn<<<dim3(8, 64, 8), 768, 0, stream>>>(Qw, Kw, Vw, XO);
    k_proj<<<dim3(12, 4, 64), 256, 0, stream>>>(XO, WpE, bp, out);
}